// Round 8
// baseline (394.100 us; speedup 1.0000x reference)
//
#include <hip/hip_runtime.h>
#include <math.h>

#define B 32
#define T 2048
#define H 512

#define BT2 64             // t rows per k2 block

typedef __attribute__((ext_vector_type(8))) __bf16 bf16x8;
typedef __attribute__((ext_vector_type(4))) __bf16 bf16x4v;
typedef __attribute__((ext_vector_type(4))) float f32x4;
typedef __attribute__((ext_vector_type(4))) float floatx4;

union pack8 { bf16x4v h; uint2 u; };
union fragU { bf16x4v q[2]; bf16x8 v; };

// ---------------- K_init: flat grid.
// blocks [0,256): GEMV q-proj (b=blk>>3, s=blk&7)
// blocks [256,288): convert v_w slice -> bf16
// block 288: zero ctx_num (B*H) and denom (B)
__global__ __launch_bounds__(256) void k_init(const float* __restrict__ query,
                                              const float* __restrict__ q_w,
                                              const float* __restrict__ bias,
                                              const float* __restrict__ v_w,
                                              float* __restrict__ qpb,
                                              unsigned short* __restrict__ wbf,
                                              float* __restrict__ ctx_num,
                                              float* __restrict__ denom) {
    const int blk = blockIdx.x;
    const int tid = threadIdx.x;

    if (blk >= 288) {
#pragma unroll
        for (int i = 0; i < 16; ++i) {
            const int off = tid * 4 + i * 1024;
            *(f32x4*)(ctx_num + off) = (f32x4){0.f, 0.f, 0.f, 0.f};
        }
        if (tid < B) denom[tid] = 0.f;
        return;
    }
    if (blk >= 256) {
        const int c = blk - 256;
        const size_t base = (size_t)c * 8192 + tid * 4;
#pragma unroll
        for (int i = 0; i < 8; ++i) {
            const size_t off = base + (size_t)i * 1024;
            f32x4 a = *(const f32x4*)(v_w + off);
            pack8 p;
            p.h = __builtin_convertvector(a, bf16x4v);
            *(uint2*)(wbf + off) = p.u;
        }
        return;
    }

    const int b = blk >> 3;
    const int s = blk & 7;
    const int wave = tid >> 6;
    const int lane = tid & 63;

    const float* qb = query + (size_t)b * H + lane * 8;
    float4 q0 = *(const float4*)qb;
    float4 q1 = *(const float4*)(qb + 4);

    const int o0 = s * 64 + wave * 16;
#pragma unroll
    for (int i = 0; i < 16; ++i) {
        const int o = o0 + i;
        const float* wr = q_w + (size_t)o * H + lane * 8;
        float4 w0 = *(const float4*)wr;
        float4 w1 = *(const float4*)(wr + 4);
        float acc = w0.x * q0.x + w0.y * q0.y + w0.z * q0.z + w0.w * q0.w +
                    w1.x * q1.x + w1.y * q1.y + w1.z * q1.z + w1.w * q1.w;
#pragma unroll
        for (int m = 1; m < 64; m <<= 1) acc += __shfl_xor(acc, m);
        if (lane == 0) qpb[b * H + o] = acc + bias[o];
    }
}

// ---------------- K2: barrier-free register GEMM.
// 512 thr = 8 waves; wave w computes 64 t x o-strip [w*64, w*64+64).
// Fragments loaded directly from global (A: value fp32 + cvt; B: wbf bf16).
// One-iteration software prefetch; NO LDS, NO barriers in the K-loop.
__global__ __launch_bounds__(512, 2) void k2_reg(const float* __restrict__ value,
                                                 const unsigned short* __restrict__ wbf,
                                                 const float* __restrict__ la,
                                                 const float* __restrict__ conv_w,
                                                 const float* __restrict__ conv_b,
                                                 const float* __restrict__ s_w,
                                                 const float* __restrict__ qpb,
                                                 const float* __restrict__ s_b,
                                                 float* __restrict__ pre_sg,
                                                 float* __restrict__ ctx_num,
                                                 float* __restrict__ denom) {
    __shared__ float las[BT2 + 2];
    __shared__ float redp[BT2][9];
    __shared__ float sgs[BT2];
    __shared__ float redc[4 * H];    // 8 KB

    const int t0 = blockIdx.x * BT2;
    const int b  = blockIdx.y;
    const int tid = threadIdx.x;
    const int wave = tid >> 6;        // 0..7
    const int lane = tid & 63;
    const int tx   = lane & 15;
    const int quad = lane >> 4;
    const int wn   = wave * 64;       // this wave's o-strip

    if (tid < BT2 + 2) {
        const int t = t0 + tid - 1;
        las[tid] = (t >= 0 && t < T) ? la[b * T + t] : 0.f;
    }

    floatx4 acc[4][4];
#pragma unroll
    for (int i = 0; i < 4; ++i)
#pragma unroll
        for (int j = 0; j < 4; ++j) acc[i][j] = (floatx4){0.f, 0.f, 0.f, 0.f};

    // fragment base pointers (per-lane)
    const float* aB = value + ((size_t)b * T + t0 + tx) * H + quad * 8;
    const unsigned short* bB = wbf + (size_t)(wn + tx) * H + quad * 8;

    // prologue: load k-chunk 0
    f32x4 alo[4], ahi[4];
    bf16x8 bfr[4];
#pragma unroll
    for (int mi = 0; mi < 4; ++mi) {
        const float* p = aB + (size_t)mi * 16 * H;
        alo[mi] = *(const f32x4*)p;
        ahi[mi] = *(const f32x4*)(p + 4);
    }
#pragma unroll
    for (int ni = 0; ni < 4; ++ni)
        bfr[ni] = *(const bf16x8*)(bB + (size_t)ni * 16 * H);

    for (int kc = 0; kc < H; kc += 32) {
        // prefetch next chunk while current chunk computes
        f32x4 nlo[4], nhi[4];
        bf16x8 nbf[4];
        if (kc + 32 < H) {
#pragma unroll
            for (int mi = 0; mi < 4; ++mi) {
                const float* p = aB + (size_t)mi * 16 * H + kc + 32;
                nlo[mi] = *(const f32x4*)p;
                nhi[mi] = *(const f32x4*)(p + 4);
            }
#pragma unroll
            for (int ni = 0; ni < 4; ++ni)
                nbf[ni] = *(const bf16x8*)(bB + (size_t)ni * 16 * H + kc + 32);
        }

        bf16x8 af[4];
#pragma unroll
        for (int mi = 0; mi < 4; ++mi) {
            fragU u;
            u.q[0] = __builtin_convertvector(alo[mi], bf16x4v);
            u.q[1] = __builtin_convertvector(ahi[mi], bf16x4v);
            af[mi] = u.v;
        }
#pragma unroll
        for (int mi = 0; mi < 4; ++mi)
#pragma unroll
            for (int ni = 0; ni < 4; ++ni)
                acc[mi][ni] = __builtin_amdgcn_mfma_f32_16x16x32_bf16(
                    af[mi], bfr[ni], acc[mi][ni], 0, 0, 0);

#pragma unroll
        for (int mi = 0; mi < 4; ++mi) { alo[mi] = nlo[mi]; ahi[mi] = nhi[mi]; }
#pragma unroll
        for (int ni = 0; ni < 4; ++ni) bfr[ni] = nbf[ni];
    }

    // epilogue constants loaded after K-loop (short live range)
    float qp4[4], sw4[4], cb4[4], c04[4], c14[4], c24[4];
#pragma unroll
    for (int ni = 0; ni < 4; ++ni) {
        const int ol = wn + ni * 16 + tx;
        qp4[ni] = qpb[b * H + ol];
        sw4[ni] = s_w[ol];
        cb4[ni] = conv_b[ol];
        c04[ni] = conv_w[ol * 3 + 0];
        c14[ni] = conv_w[ol * 3 + 1];
        c24[ni] = conv_w[ol * 3 + 2];
    }

    float sacc[16];
#pragma unroll
    for (int i = 0; i < 16; ++i) sacc[i] = 0.f;
#pragma unroll
    for (int ni = 0; ni < 4; ++ni) {
#pragma unroll
        for (int mi = 0; mi < 4; ++mi)
#pragma unroll
            for (int r = 0; r < 4; ++r) {
                const int tl = mi * 16 + quad * 4 + r;
                const float conv = c04[ni] * las[tl] + c14[ni] * las[tl + 1] +
                                   c24[ni] * las[tl + 2] + cb4[ni];
                const float x = acc[mi][ni][r] + qp4[ni] + conv;
                const float ex = __expf(2.f * x);
                const float th = 1.f - 2.f * __builtin_amdgcn_rcpf(ex + 1.f);
                sacc[mi * 4 + r] += sw4[ni] * th;
            }
    }
#pragma unroll
    for (int i = 0; i < 16; ++i) {
        float v = sacc[i];
        v += __shfl_xor(v, 1);
        v += __shfl_xor(v, 2);
        v += __shfl_xor(v, 4);
        v += __shfl_xor(v, 8);
        if (tx == 0) redp[(i >> 2) * 16 + quad * 4 + (i & 3)][wave] = v;
    }
    __syncthreads();

    // wave 0: score -> sigmoid -> sgs + pre_sg + denom atomic
    if (tid < BT2) {
        float sc = s_b[0];
#pragma unroll
        for (int w = 0; w < 8; ++w) sc += redp[tid][w];
        const float sg = 1.f / (1.f + __expf(-sc));
        sgs[tid] = sg;
        pre_sg[b * T + t0 + tid] = sg;
        float dsum = sg;
#pragma unroll
        for (int m = 1; m < 64; m <<= 1) dsum += __shfl_xor(dsum, m);
        if (tid == 0) atomicAdd(&denom[b], dsum);
    }
    __syncthreads();

    // ctx partial: num[h] += sum_t sgs[t]*value[t][h] (value tile L2-hot)
    const int h4 = (tid & 127) * 4;
    const int tp = tid >> 7;          // 0..3
    f32x4 a = {0.f, 0.f, 0.f, 0.f};
    const float* vb = value + ((size_t)b * T + t0) * H + h4;
    for (int t = tp; t < BT2; t += 4) {
        const float w = sgs[t];
        f32x4 v = *(const f32x4*)(vb + (size_t)t * H);
        a.x += w * v.x; a.y += w * v.y; a.z += w * v.z; a.w += w * v.w;
    }
    *(f32x4*)&redc[tp * H + h4] = a;
    __syncthreads();
    if (tid < 128) {
        const int h = tid * 4;
        f32x4 r0 = *(const f32x4*)&redc[0 * H + h];
        f32x4 r1 = *(const f32x4*)&redc[1 * H + h];
        f32x4 r2 = *(const f32x4*)&redc[2 * H + h];
        f32x4 r3 = *(const f32x4*)&redc[3 * H + h];
        atomicAdd(&ctx_num[b * H + h + 0], r0.x + r1.x + r2.x + r3.x);
        atomicAdd(&ctx_num[b * H + h + 1], r0.y + r1.y + r2.y + r3.y);
        atomicAdd(&ctx_num[b * H + h + 2], r0.z + r1.z + r2.z + r3.z);
        atomicAdd(&ctx_num[b * H + h + 3], r0.w + r1.w + r2.w + r3.w);
    }
}

// ---------------- K3: scale by 1/denom
__global__ __launch_bounds__(256) void k3_scale(const float* __restrict__ pre_sg,
                                                const float* __restrict__ ctx_num,
                                                const float* __restrict__ denom,
                                                float* __restrict__ attn_out,
                                                float* __restrict__ ctx) {
    const int b = blockIdx.x;
    const int tid = threadIdx.x;
    const float inv = 1.f / denom[b];
#pragma unroll
    for (int i = 0; i < 8; ++i) {
        const int t = tid + i * 256;
        attn_out[b * T + t] = pre_sg[b * T + t] * inv;
    }
#pragma unroll
    for (int i = 0; i < 2; ++i) {
        const int h = tid + i * 256;
        ctx[b * H + h] = ctx_num[b * H + h] * inv;
    }
}

extern "C" void kernel_launch(void* const* d_in, const int* in_sizes, int n_in,
                              void* d_out, int out_size, void* d_ws, size_t ws_size,
                              hipStream_t stream) {
    const float* query  = (const float*)d_in[0];
    const float* value  = (const float*)d_in[1];
    const float* la     = (const float*)d_in[2];
    const float* conv_w = (const float*)d_in[3];
    const float* conv_b = (const float*)d_in[4];
    const float* q_w    = (const float*)d_in[5];
    const float* v_w    = (const float*)d_in[6];
    const float* s_w    = (const float*)d_in[7];
    const float* s_b    = (const float*)d_in[8];
    const float* bias   = (const float*)d_in[9];

    float* out  = (float*)d_out;
    float* ctx  = out;            // (B, H)
    float* attn = out + B * H;    // (B, T)

    float* qpb     = (float*)d_ws;                 // B*H
    float* pre_sg  = qpb + B * H;                  // B*T
    float* ctx_num = pre_sg + B * T;               // B*H
    float* denom   = ctx_num + B * H;              // B
    unsigned short* wbf = (unsigned short*)(denom + 64);   // H*H bf16

    k_init<<<289, 256, 0, stream>>>(query, q_w, bias, v_w, qpb, wbf, ctx_num, denom);

    dim3 g2(T / BT2, B);
    k2_reg<<<g2, 512, 0, stream>>>(value, wbf, la, conv_w, conv_b, s_w, qpb, s_b,
                                   pre_sg, ctx_num, denom);

    k3_scale<<<B, 256, 0, stream>>>(pre_sg, ctx_num, denom, attn, ctx);
}

// Round 9
// 293.066 us; speedup vs baseline: 1.3447x; 1.3447x over previous
//
#include <hip/hip_runtime.h>
#include <math.h>

#define B 32
#define T 2048
#define H 512

#define BT2 64             // t rows per k2 block

typedef __attribute__((ext_vector_type(8))) __bf16 bf16x8;
typedef __attribute__((ext_vector_type(4))) __bf16 bf16x4v;
typedef __attribute__((ext_vector_type(4))) float f32x4;
typedef __attribute__((ext_vector_type(4))) float floatx4;

union pack8 { bf16x4v h; uint2 u; };
union fragU { bf16x4v q[2]; bf16x8 v; };

static __device__ __forceinline__ void gl_lds16(const void* g, void* l) {
    __builtin_amdgcn_global_load_lds(
        (const __attribute__((address_space(1))) void*)g,
        (__attribute__((address_space(3))) void*)l, 16, 0, 0);
}

// ---------------- K_init: flat grid.
// blocks [0,256): GEMV q-proj (b=blk>>3, s=blk&7)
// blocks [256,288): convert v_w slice -> bf16
// block 288: zero ctx_num (B*H) and denom (B)
__global__ __launch_bounds__(256) void k_init(const float* __restrict__ query,
                                              const float* __restrict__ q_w,
                                              const float* __restrict__ bias,
                                              const float* __restrict__ v_w,
                                              float* __restrict__ qpb,
                                              unsigned short* __restrict__ wbf,
                                              float* __restrict__ ctx_num,
                                              float* __restrict__ denom) {
    const int blk = blockIdx.x;
    const int tid = threadIdx.x;

    if (blk >= 288) {
#pragma unroll
        for (int i = 0; i < 16; ++i) {
            const int off = tid * 4 + i * 1024;
            *(f32x4*)(ctx_num + off) = (f32x4){0.f, 0.f, 0.f, 0.f};
        }
        if (tid < B) denom[tid] = 0.f;
        return;
    }
    if (blk >= 256) {
        const int c = blk - 256;
        const size_t base = (size_t)c * 8192 + tid * 4;
#pragma unroll
        for (int i = 0; i < 8; ++i) {
            const size_t off = base + (size_t)i * 1024;
            f32x4 a = *(const f32x4*)(v_w + off);
            pack8 p;
            p.h = __builtin_convertvector(a, bf16x4v);
            *(uint2*)(wbf + off) = p.u;
        }
        return;
    }

    const int b = blk >> 3;
    const int s = blk & 7;
    const int wave = tid >> 6;
    const int lane = tid & 63;

    const float* qb = query + (size_t)b * H + lane * 8;
    float4 q0 = *(const float4*)qb;
    float4 q1 = *(const float4*)(qb + 4);

    const int o0 = s * 64 + wave * 16;
#pragma unroll
    for (int i = 0; i < 16; ++i) {
        const int o = o0 + i;
        const float* wr = q_w + (size_t)o * H + lane * 8;
        float4 w0 = *(const float4*)wr;
        float4 w1 = *(const float4*)(wr + 4);
        float acc = w0.x * q0.x + w0.y * q0.y + w0.z * q0.z + w0.w * q0.w +
                    w1.x * q1.x + w1.y * q1.y + w1.z * q1.z + w1.w * q1.w;
#pragma unroll
        for (int m = 1; m < 64; m <<= 1) acc += __shfl_xor(acc, m);
        if (lane == 0) qpb[b * H + o] = acc + bias[o];
    }
}

// ---------------- K2: 64t x 512o; ALL-glds staging (A fp32 swizzled, B bf16 swizzled),
// conversion at fragment-read time; score+sigmoid+ctx fused (R7 epilogue).
__global__ __launch_bounds__(512, 2) void k2_glds(const float* __restrict__ value,
                                                  const unsigned short* __restrict__ wbf,
                                                  const float* __restrict__ la,
                                                  const float* __restrict__ conv_w,
                                                  const float* __restrict__ conv_b,
                                                  const float* __restrict__ s_w,
                                                  const float* __restrict__ qpb,
                                                  const float* __restrict__ s_b,
                                                  float* __restrict__ pre_sg,
                                                  float* __restrict__ ctx_num,
                                                  float* __restrict__ denom) {
    // A: 64 rows x 32 fp32, stored as 512 16B-slots, slot = row*8 + (c ^ (row&7))
    __shared__ __align__(16) float As[BT2 * 32];              // 8 KB
    // B: 512 rows x 32 bf16, 2048 slots, slot = row*4 + (c ^ ((row>>1)&3))
    __shared__ __align__(16) unsigned short Bs[H * 32];       // 32 KB
    __shared__ float las[BT2 + 2];
    __shared__ float redp[BT2][9];
    __shared__ float sgs[BT2];

    const int t0 = blockIdx.x * BT2;
    const int b  = blockIdx.y;
    const int tid = threadIdx.x;
    const int wave = tid >> 6;        // 0..7
    const int lane = tid & 63;
    const int tx   = lane & 15;
    const int quad = lane >> 4;
    const int wn   = wave * 64;       // this wave's o-strip

    if (tid < BT2 + 2) {
        const int t = t0 + tid - 1;
        las[tid] = (t >= 0 && t < T) ? la[b * T + t] : 0.f;
    }

    floatx4 acc[4][4];
#pragma unroll
    for (int i = 0; i < 4; ++i)
#pragma unroll
        for (int j = 0; j < 4; ++j) acc[i][j] = (floatx4){0.f, 0.f, 0.f, 0.f};

    // ---- staging source pointers (swizzle applied to SOURCE; dst is contiguous)
    // A: slot sA = wave*64 + lane; row=sA>>3, c'=sA&7, c=c'^(row&7)
    const int sA = wave * 64 + lane;
    const int aRow = sA >> 3;
    const int aC   = (sA & 7) ^ (aRow & 7);
    const float* gA = value + ((size_t)b * T + t0 + aRow) * H + aC * 4;
    char* lA = (char*)As + (size_t)wave * 1024;

    // B: glds j (0..3): slot sB = (j*8+wave)*64 + lane; row=sB>>2, c'=sB&3,
    //    c = c' ^ ((row>>1)&3)
    const unsigned short* gB[4];
    char* lB[4];
#pragma unroll
    for (int j = 0; j < 4; ++j) {
        const int sB = (j * 8 + wave) * 64 + lane;
        const int bRow = sB >> 2;
        const int bC   = (sB & 3) ^ ((bRow >> 1) & 3);
        gB[j] = wbf + (size_t)bRow * H + bC * 8;
        lB[j] = (char*)Bs + (size_t)(j * 8 + wave) * 1024;
    }

    // ---- fragment-read LDS offsets (bytes), constant over kc
    int aOff[4][2];
#pragma unroll
    for (int mi = 0; mi < 4; ++mi) {
        const int R = mi * 16 + tx;
#pragma unroll
        for (int j = 0; j < 2; ++j)
            aOff[mi][j] = (R * 8 + ((2 * quad + j) ^ (R & 7))) * 16;
    }
    int bOff[4];
#pragma unroll
    for (int ni = 0; ni < 4; ++ni) {
        const int R = wn + ni * 16 + tx;
        bOff[ni] = (R * 4 + (quad ^ ((R >> 1) & 3))) * 16;
    }

    for (int kc = 0; kc < H; kc += 32) {
        __syncthreads();              // prior frag reads complete
        gl_lds16(gA + kc, lA);
#pragma unroll
        for (int j = 0; j < 4; ++j) gl_lds16(gB[j] + kc, lB[j]);
        __syncthreads();              // staging visible

        bf16x8 af[4], bfr[4];
#pragma unroll
        for (int mi = 0; mi < 4; ++mi) {
            f32x4 lo = *(const f32x4*)((const char*)As + aOff[mi][0]);
            f32x4 hi = *(const f32x4*)((const char*)As + aOff[mi][1]);
            fragU u;
            u.q[0] = __builtin_convertvector(lo, bf16x4v);
            u.q[1] = __builtin_convertvector(hi, bf16x4v);
            af[mi] = u.v;
        }
#pragma unroll
        for (int ni = 0; ni < 4; ++ni)
            bfr[ni] = *(const bf16x8*)((const char*)Bs + bOff[ni]);

#pragma unroll
        for (int mi = 0; mi < 4; ++mi)
#pragma unroll
            for (int ni = 0; ni < 4; ++ni)
                acc[mi][ni] = __builtin_amdgcn_mfma_f32_16x16x32_bf16(
                    af[mi], bfr[ni], acc[mi][ni], 0, 0, 0);
    }

    // epilogue constants (loaded after K-loop: short live range)
    float qp4[4], sw4[4], cb4[4], c04[4], c14[4], c24[4];
#pragma unroll
    for (int ni = 0; ni < 4; ++ni) {
        const int ol = wn + ni * 16 + tx;
        qp4[ni] = qpb[b * H + ol];
        sw4[ni] = s_w[ol];
        cb4[ni] = conv_b[ol];
        c04[ni] = conv_w[ol * 3 + 0];
        c14[ni] = conv_w[ol * 3 + 1];
        c24[ni] = conv_w[ol * 3 + 2];
    }

    float sacc[16];
#pragma unroll
    for (int i = 0; i < 16; ++i) sacc[i] = 0.f;
#pragma unroll
    for (int ni = 0; ni < 4; ++ni) {
#pragma unroll
        for (int mi = 0; mi < 4; ++mi)
#pragma unroll
            for (int r = 0; r < 4; ++r) {
                const int tl = mi * 16 + quad * 4 + r;
                const float conv = c04[ni] * las[tl] + c14[ni] * las[tl + 1] +
                                   c24[ni] * las[tl + 2] + cb4[ni];
                const float x = acc[mi][ni][r] + qp4[ni] + conv;
                const float ex = __expf(2.f * x);
                const float th = 1.f - 2.f * __builtin_amdgcn_rcpf(ex + 1.f);
                sacc[mi * 4 + r] += sw4[ni] * th;
            }
    }
#pragma unroll
    for (int i = 0; i < 16; ++i) {
        float v = sacc[i];
        v += __shfl_xor(v, 1);
        v += __shfl_xor(v, 2);
        v += __shfl_xor(v, 4);
        v += __shfl_xor(v, 8);
        if (tx == 0) redp[(i >> 2) * 16 + quad * 4 + (i & 3)][wave] = v;
    }
    __syncthreads();

    // wave 0: score -> sigmoid -> sgs + pre_sg + denom atomic
    if (tid < BT2) {
        float sc = s_b[0];
#pragma unroll
        for (int w = 0; w < 8; ++w) sc += redp[tid][w];
        const float sg = 1.f / (1.f + __expf(-sc));
        sgs[tid] = sg;
        pre_sg[b * T + t0 + tid] = sg;
        float dsum = sg;
#pragma unroll
        for (int m = 1; m < 64; m <<= 1) dsum += __shfl_xor(dsum, m);
        if (tid == 0) atomicAdd(&denom[b], dsum);
    }
    __syncthreads();                  // sgs visible; Bs free for overlay

    // ctx partial: num[h] += sum_t sgs[t]*value[t][h] (tile L2-hot); redc overlays Bs
    float* redc = (float*)Bs;
    const int h4 = (tid & 127) * 4;
    const int tp = tid >> 7;          // 0..3
    f32x4 a = {0.f, 0.f, 0.f, 0.f};
    const float* vb = value + ((size_t)b * T + t0) * H + h4;
    for (int t = tp; t < BT2; t += 4) {
        const float w = sgs[t];
        f32x4 v = *(const f32x4*)(vb + (size_t)t * H);
        a.x += w * v.x; a.y += w * v.y; a.z += w * v.z; a.w += w * v.w;
    }
    *(f32x4*)&redc[tp * H + h4] = a;
    __syncthreads();
    if (tid < 128) {
        const int h = tid * 4;
        f32x4 r0 = *(const f32x4*)&redc[0 * H + h];
        f32x4 r1 = *(const f32x4*)&redc[1 * H + h];
        f32x4 r2 = *(const f32x4*)&redc[2 * H + h];
        f32x4 r3 = *(const f32x4*)&redc[3 * H + h];
        atomicAdd(&ctx_num[b * H + h + 0], r0.x + r1.x + r2.x + r3.x);
        atomicAdd(&ctx_num[b * H + h + 1], r0.y + r1.y + r2.y + r3.y);
        atomicAdd(&ctx_num[b * H + h + 2], r0.z + r1.z + r2.z + r3.z);
        atomicAdd(&ctx_num[b * H + h + 3], r0.w + r1.w + r2.w + r3.w);
    }
}

// ---------------- K3: scale by 1/denom
__global__ __launch_bounds__(256) void k3_scale(const float* __restrict__ pre_sg,
                                                const float* __restrict__ ctx_num,
                                                const float* __restrict__ denom,
                                                float* __restrict__ attn_out,
                                                float* __restrict__ ctx) {
    const int b = blockIdx.x;
    const int tid = threadIdx.x;
    const float inv = 1.f / denom[b];
#pragma unroll
    for (int i = 0; i < 8; ++i) {
        const int t = tid + i * 256;
        attn_out[b * T + t] = pre_sg[b * T + t] * inv;
    }
#pragma unroll
    for (int i = 0; i < 2; ++i) {
        const int h = tid + i * 256;
        ctx[b * H + h] = ctx_num[b * H + h] * inv;
    }
}

extern "C" void kernel_launch(void* const* d_in, const int* in_sizes, int n_in,
                              void* d_out, int out_size, void* d_ws, size_t ws_size,
                              hipStream_t stream) {
    const float* query  = (const float*)d_in[0];
    const float* value  = (const float*)d_in[1];
    const float* la     = (const float*)d_in[2];
    const float* conv_w = (const float*)d_in[3];
    const float* conv_b = (const float*)d_in[4];
    const float* q_w    = (const float*)d_in[5];
    const float* v_w    = (const float*)d_in[6];
    const float* s_w    = (const float*)d_in[7];
    const float* s_b    = (const float*)d_in[8];
    const float* bias   = (const float*)d_in[9];

    float* out  = (float*)d_out;
    float* ctx  = out;            // (B, H)
    float* attn = out + B * H;    // (B, T)

    float* qpb     = (float*)d_ws;                 // B*H
    float* pre_sg  = qpb + B * H;                  // B*T
    float* ctx_num = pre_sg + B * T;               // B*H
    float* denom   = ctx_num + B * H;              // B
    unsigned short* wbf = (unsigned short*)(denom + 64);   // H*H bf16

    k_init<<<289, 256, 0, stream>>>(query, q_w, bias, v_w, qpb, wbf, ctx_num, denom);

    dim3 g2(T / BT2, B);
    k2_glds<<<g2, 512, 0, stream>>>(value, wbf, la, conv_w, conv_b, s_w, qpb, s_b,
                                    pre_sg, ctx_num, denom);

    k3_scale<<<B, 256, 0, stream>>>(pre_sg, ctx_num, denom, attn, ctx);
}